// Round 14
// baseline (846.057 us; speedup 1.0000x reference)
//
#include <hip/hip_runtime.h>
#include <cstddef>

#define SS 2048
#define BB 256
#define II 64
#define HH 128
#define GROUP 16
#define NG (SS / GROUP)

typedef _Float16 h8 __attribute__((ext_vector_type(8)));
typedef _Float16 h2 __attribute__((ext_vector_type(2)));
typedef float    f4 __attribute__((ext_vector_type(4)));
typedef __fp16   fp16v2 __attribute__((ext_vector_type(2)));

__device__ __forceinline__ h2 pack_f16(float a, float b) {
  union { fp16v2 raw; h2 out; } cv;
  cv.raw = __builtin_amdgcn_cvt_pkrtz(a, b);  // RTZ, matches R8..R13
  return cv.out;
}
__device__ __forceinline__ float fast_rcp(float v) {
  return __builtin_amdgcn_rcpf(v);
}

#define KEEPA(x) asm volatile("" : "+a"(x))
#define KEEPV(x) asm volatile("" : "+v"(x))

// MFMA, A-operand read DIRECTLY from AGPR
__device__ __forceinline__ f4 mfma_first(const h8& a, const h8& b, const f4& c) {
  f4 d;
  asm volatile("v_mfma_f32_16x16x32_f16 %0, %1, %2, %3"
               : "=&v"(d) : "a"(a), "v"(b), "v"(c));
  return d;
}
__device__ __forceinline__ void mfma_acc(f4& d, const h8& a, const h8& b) {
  asm volatile("v_mfma_f32_16x16x32_f16 %0, %1, %2, %0"
               : "+v"(d) : "a"(a), "v"(b));
}

// LDS-only barrier (global prefetch loads stay in flight)
__device__ __forceinline__ void lds_barrier() {
  asm volatile("s_waitcnt lgkmcnt(0)" ::: "memory");
  __builtin_amdgcn_s_barrier();
}

// One workgroup per batch element; 512 threads = 8 waves; grid 256 = 1 block/CU.
// hh per step: 12 MFMA/wave in TWO PARALLEL 2-deep chains per gate
//   {bias->k0->k1} + {0->k2->k3}, joined by one f4 add post-fence.
//   (R13's single 4-deep chain put ~100 cyc of serial MAI latency per step;
//   2048 steps x 8-wave lockstep means chain latency is wall time.)
// ih: merged into tau=0 of each 16-step group; gx[gate][hu][17] f32, <=2-way.
__global__ __launch_bounds__(512) void gru_fused(
    const float* __restrict__ x,        // [B,S,I]
    const int*   __restrict__ mask,     // [B,S,I]
    const float* __restrict__ x_mean,   // [I]
    const float* __restrict__ w_ih,     // [3H,I]
    const float* __restrict__ w_hh,     // [3H,H]
    const float* __restrict__ b_ih,     // [3H]
    const float* __restrict__ b_hh,     // [3H]
    const float* __restrict__ bn_gamma, // [H]
    const float* __restrict__ bn_beta,  // [H]
    const float* __restrict__ bn_mean,  // [H]
    const float* __restrict__ bn_var,   // [H]
    const float* __restrict__ fc_w,     // [1,H]
    const float* __restrict__ fc_b,     // [1]
    float* __restrict__ out)            // [B,1]
{
  const int b   = blockIdx.x;
  const int tid = threadIdx.x;
  const int wv  = tid >> 6;   // wave 0..7
  const int l   = tid & 63;
  const int col = l & 15;     // A row / C-col (= tau in ih-GEMM)
  const int grp = l >> 4;     // k-group

  __shared__ __align__(16) _Float16 h_lds[2][HH];
  __shared__ __align__(16) _Float16 xi_st[GROUP][72];  // [tau][chan], +8 pad
  __shared__ float gx_lds[3][HH][17];                  // [gate][hu][tau], pad 17
  __shared__ float h_fin[HH];

  // ---- A-fragments (weights) -> AGPRs, loaded once ----
  h8 whA[3][4];  // g in {r,z,n} x 4 k-tiles (K=128)
  h8 wiA[3][2];  // g x 2 k-tiles (K=64)
  #pragma unroll
  for (int g = 0; g < 3; ++g) {
    const int row = g * HH + wv * 16 + col;
    #pragma unroll
    for (int kt = 0; kt < 4; ++kt) {
      const float* pw = w_hh + (size_t)row * HH + kt * 32 + grp * 8;
      float4 va = *reinterpret_cast<const float4*>(pw);
      float4 vb = *reinterpret_cast<const float4*>(pw + 4);
      h8 f;
      f[0]=(_Float16)va.x; f[1]=(_Float16)va.y; f[2]=(_Float16)va.z; f[3]=(_Float16)va.w;
      f[4]=(_Float16)vb.x; f[5]=(_Float16)vb.y; f[6]=(_Float16)vb.z; f[7]=(_Float16)vb.w;
      whA[g][kt] = f;
    }
    #pragma unroll
    for (int kt = 0; kt < 2; ++kt) {
      const float* pw = w_ih + (size_t)row * II + kt * 32 + grp * 8;
      float4 va = *reinterpret_cast<const float4*>(pw);
      float4 vb = *reinterpret_cast<const float4*>(pw + 4);
      h8 f;
      f[0]=(_Float16)va.x; f[1]=(_Float16)va.y; f[2]=(_Float16)va.z; f[3]=(_Float16)va.w;
      f[4]=(_Float16)vb.x; f[5]=(_Float16)vb.y; f[6]=(_Float16)vb.z; f[7]=(_Float16)vb.w;
      wiA[g][kt] = f;
    }
  }
  #pragma unroll
  for (int g = 0; g < 3; ++g) {
    #pragma unroll
    for (int kt = 0; kt < 4; ++kt) KEEPA(whA[g][kt]);
    #pragma unroll
    for (int kt = 0; kt < 2; ++kt) KEEPA(wiA[g][kt]);
  }

  // bias C-init fragments (hh chain A starts from bias; chain B from zero)
  f4 bRf, bZf, bNXf, bNHf;
  #pragma unroll
  for (int q = 0; q < 4; ++q) {
    const int hu = wv * 16 + grp * 4 + q;
    bRf[q]  = b_ih[hu]        + b_hh[hu];
    bZf[q]  = b_ih[HH + hu]   + b_hh[HH + hu];
    bNXf[q] = b_ih[2*HH + hu];
    bNHf[q] = b_hh[2*HH + hu];
  }
  f4 zf = {0.f, 0.f, 0.f, 0.f};
  KEEPV(bRf); KEEPV(bZf); KEEPV(bNXf); KEEPV(bNHf); KEEPV(zf);

  // per-lane gate slot
  const int q_l  = col & 3;
  const int hu_l = wv * 16 + grp * 4 + q_l;
  const bool cs1 = (col & 1) != 0;
  const bool cs2 = (col & 2) != 0;
  const bool wlead = (col < 4);
  const int hub = wv * 16 + grp * 4;   // gx-write row base

  // ---- LOCF staging: wave 0 (tid<64), one channel each ----
  const size_t xbase = (size_t)b * SS * II;
  const float* xg = x + xbase;
  const int*   mg = mask + xbase;
  float last = 0.f;
  float x_stg[16];
  int   m_stg[16];
  if (tid < 64) {
    last = x_mean[tid];
    #pragma unroll
    for (int u = 0; u < GROUP; ++u) {
      x_stg[u] = xg[u * II + tid];
      m_stg[u] = mg[u * II + tid];
    }
  }
  float ho = 0.f;  // h[t-1][hu_l], f32

  for (int gq = 0; gq < NG; ++gq) {
    // wave0: LOCF -> xi_st (pre-barrier; consumed by all at tau0 post-barrier)
    if (tid < 64) {
      #pragma unroll
      for (int u = 0; u < GROUP; ++u) {
        last = (m_stg[u] > 0) ? x_stg[u] : last;
        xi_st[u][tid] = pack_f16(last, last).x;
      }
    }

    #pragma unroll
    for (int tau = 0; tau < GROUP; ++tau) {
      const int p = tau & 1;
      if (wlead) h_lds[p][hu_l] = pack_f16(ho, ho).x;
      lds_barrier();  // covers h (and xi_st at tau0)

      if (tau == 0) {
        // prefetch next group's x/mask (stays in flight; vmcnt not drained)
        if (tid < 64 && gq + 1 < NG) {
          const float* xn = xg + (size_t)(gq + 1) * GROUP * II;
          const int*   mn = mg + (size_t)(gq + 1) * GROUP * II;
          #pragma unroll
          for (int u = 0; u < GROUP; ++u) {
            x_stg[u] = xn[u * II + tid];
            m_stg[u] = mn[u * II + tid];
          }
        }
      }

      // gx reads hoisted (tau>=1): latency hides under MFMA issue
      float gxR, gxZ, sNX;
      if (tau != 0) {
        gxR = gx_lds[0][hu_l][tau];
        gxZ = gx_lds[1][hu_l][tau];
        sNX = gx_lds[2][hu_l][tau];
      }

      h8 hB[4];
      #pragma unroll
      for (int kt = 0; kt < 4; ++kt)
        hB[kt] = *reinterpret_cast<const h8*>(&h_lds[p][kt * 32 + grp * 8]);

      // 12 hh MFMAs: two parallel 2-deep chains per gate (halved MAI latency)
      f4 aR  = mfma_first(whA[0][0], hB[0], bRf);
      f4 aZ  = mfma_first(whA[1][0], hB[0], bZf);
      f4 aNH = mfma_first(whA[2][0], hB[0], bNHf);
      f4 cR  = mfma_first(whA[0][2], hB[2], zf);
      f4 cZ  = mfma_first(whA[1][2], hB[2], zf);
      f4 cNH = mfma_first(whA[2][2], hB[2], zf);
      mfma_acc(aR,  whA[0][1], hB[1]);
      mfma_acc(aZ,  whA[1][1], hB[1]);
      mfma_acc(aNH, whA[2][1], hB[1]);
      mfma_acc(cR,  whA[0][3], hB[3]);
      mfma_acc(cZ,  whA[1][3], hB[3]);
      mfma_acc(cNH, whA[2][3], hB[3]);

      if (tau == 0) {
        // ih-GEMM merged in: 6 MFMAs; chains identical to R12/R13
        h8 xB0 = *reinterpret_cast<const h8*>(&xi_st[col][grp * 8]);
        h8 xB1 = *reinterpret_cast<const h8*>(&xi_st[col][32 + grp * 8]);
        f4 gR  = mfma_first(wiA[0][0], xB0, zf);
        f4 gZ  = mfma_first(wiA[1][0], xB0, zf);
        f4 gNX = mfma_first(wiA[2][0], xB0, bNXf);
        mfma_acc(gR,  wiA[0][1], xB1);
        mfma_acc(gZ,  wiA[1][1], xB1);
        mfma_acc(gNX, wiA[2][1], xB1);
        asm volatile("s_nop 7\n\ts_nop 7");
        __builtin_amdgcn_sched_barrier(0);
        // gx writes: [gate][hu][tau=col] b32; intra-wave data
        #pragma unroll
        for (int q = 0; q < 4; ++q) {
          gx_lds[0][hub + q][col] = gR[q];
          gx_lds[1][hub + q][col] = gZ[q];
          gx_lds[2][hub + q][col] = gNX[q];
        }
        asm volatile("s_waitcnt lgkmcnt(0)" ::: "memory");
        __builtin_amdgcn_sched_barrier(0);
        gxR = gx_lds[0][hu_l][0];
        gxZ = gx_lds[1][hu_l][0];
        sNX = gx_lds[2][hu_l][0];
      } else {
        asm volatile("s_nop 7\n\ts_nop 7");
        __builtin_amdgcn_sched_barrier(0);
      }

      // join the parallel chains (one f4 add per gate; pk_add-fusable)
      aR  += cR;
      aZ  += cZ;
      aNH += cNH;

      // dedup selects (masks loop-invariant) + gate math (unchanged since R8)
      const float sR  = (cs2 ? (cs1 ? aR[3]  : aR[2])  : (cs1 ? aR[1]  : aR[0]))  + gxR;
      const float sZ  = (cs2 ? (cs1 ? aZ[3]  : aZ[2])  : (cs1 ? aZ[1]  : aZ[0]))  + gxZ;
      const float sNH =  cs2 ? (cs1 ? aNH[3] : aNH[2]) : (cs1 ? aNH[1] : aNH[0]);

      float r = fast_rcp(1.f + __expf(-sR));
      float z = fast_rcp(1.f + __expf(-sZ));
      float a = sNX + r * sNH;
      float n = 1.f - 2.f * fast_rcp(__expf(2.f * a) + 1.f);
      ho = n + z * (ho - n);
    }
  }

  // publish final h (f32)
  if (wlead) h_fin[hu_l] = ho;
  __syncthreads();

  // BN (eval) + FC, reduced by wave 0
  if (tid < 64) {
    float pacc = 0.f;
    #pragma unroll
    for (int q = 0; q < 2; ++q) {
      const int k = tid + q * 64;
      const float hv2 = h_fin[k];
      const float nrm = (hv2 - bn_mean[k]) * rsqrtf(bn_var[k] + 1e-5f) * bn_gamma[k] + bn_beta[k];
      pacc += nrm * fc_w[k];
    }
    #pragma unroll
    for (int off = 32; off > 0; off >>= 1) pacc += __shfl_down(pacc, off);
    if (tid == 0) out[b] = pacc + fc_b[0];
  }
}

extern "C" void kernel_launch(void* const* d_in, const int* in_sizes, int n_in,
                              void* d_out, int out_size, void* d_ws, size_t ws_size,
                              hipStream_t stream) {
  const float* x        = (const float*)d_in[0];
  const int*   mask     = (const int*)  d_in[1];
  // d_in[2] = delta (unused by reference forward)
  const float* x_mean   = (const float*)d_in[3];
  const float* w_ih     = (const float*)d_in[4];
  const float* w_hh     = (const float*)d_in[5];
  const float* b_ih     = (const float*)d_in[6];
  const float* b_hh     = (const float*)d_in[7];
  const float* bn_gamma = (const float*)d_in[8];
  const float* bn_beta  = (const float*)d_in[9];
  const float* bn_mean  = (const float*)d_in[10];
  const float* bn_var   = (const float*)d_in[11];
  const float* fc_w     = (const float*)d_in[12];
  const float* fc_b     = (const float*)d_in[13];
  float* out = (float*)d_out;

  gru_fused<<<dim3(BB), dim3(512), 0, stream>>>(
      x, mask, x_mean, w_ih, w_hh, b_ih, b_hh,
      bn_gamma, bn_beta, bn_mean, bn_var, fc_w, fc_b, out);
}

// Round 15
// 766.186 us; speedup vs baseline: 1.1042x; 1.1042x over previous
//
#include <hip/hip_runtime.h>
#include <cstddef>

#define SS 2048
#define BB 256
#define II 64
#define HH 128
#define GROUP 16
#define NG (SS / GROUP)

typedef _Float16 h8 __attribute__((ext_vector_type(8)));
typedef _Float16 h2 __attribute__((ext_vector_type(2)));
typedef float    f4 __attribute__((ext_vector_type(4)));
typedef __fp16   fp16v2 __attribute__((ext_vector_type(2)));

__device__ __forceinline__ h2 pack_f16(float a, float b) {
  union { fp16v2 raw; h2 out; } cv;
  cv.raw = __builtin_amdgcn_cvt_pkrtz(a, b);  // RTZ, matches R8..R13
  return cv.out;
}
__device__ __forceinline__ float fast_rcp(float v) {
  return __builtin_amdgcn_rcpf(v);
}

#define KEEPA(x) asm volatile("" : "+a"(x))
#define KEEPV(x) asm volatile("" : "+v"(x))

// MFMA, A-operand read DIRECTLY from AGPR
__device__ __forceinline__ f4 mfma_first(const h8& a, const h8& b, const f4& c) {
  f4 d;
  asm volatile("v_mfma_f32_16x16x32_f16 %0, %1, %2, %3"
               : "=&v"(d) : "a"(a), "v"(b), "v"(c));
  return d;
}
__device__ __forceinline__ void mfma_acc(f4& d, const h8& a, const h8& b) {
  asm volatile("v_mfma_f32_16x16x32_f16 %0, %1, %2, %0"
               : "+v"(d) : "a"(a), "v"(b));
}

// select q=col&3 from acc + add gx + exp(-x) start:  returns exp2(-(sel+gx)*log2e)
// Placed as volatile asm so its position in the MFMA issue stream is exact:
// >=4 MFMA issues after its producer cluster (+s_nop 2) covers the
// MFMA-DstD->VALU hazard; trailing s_nop 1 covers the trans->VALU hazard.
// Select tree + add + mul(-log2e) + exp is the SAME op sequence R13's C++
// compiled to -> bit-identical results.
__device__ __forceinline__ float sel_exp(const f4& a, float gx) {
  float o, t;
  asm volatile(
      "s_nop 2\n\t"
      "v_cndmask_b32 %0, %2, %3, %6\n\t"   // cs1 ? a1 : a0
      "v_cndmask_b32 %1, %4, %5, %6\n\t"   // cs1 ? a3 : a2
      "v_cndmask_b32 %0, %0, %1, %7\n\t"   // cs2 ? t1 : t0
      "v_add_f32 %0, %0, %8\n\t"           // + gx
      "v_mul_f32 %0, 0xbfb8aa3b, %0\n\t"   // * -log2(e)
      "v_exp_f32 %0, %0\n\t"
      "s_nop 1"
      : "=&v"(o), "=&v"(t)
      : "v"(a[0]), "v"(a[1]), "v"(a[2]), "v"(a[3]),
        "s"(0xAAAAAAAAAAAAAAAAull),        // lanes with (l&1)  -> cs1
        "s"(0xCCCCCCCCCCCCCCCCull),        // lanes with (l&2)  -> cs2
        "v"(gx));
  return o;
}
// select-only (for NH)
__device__ __forceinline__ float sel_nh(const f4& a) {
  float o, t;
  asm volatile(
      "s_nop 2\n\t"
      "v_cndmask_b32 %0, %2, %3, %6\n\t"
      "v_cndmask_b32 %1, %4, %5, %6\n\t"
      "v_cndmask_b32 %0, %0, %1, %7"
      : "=&v"(o), "=&v"(t)
      : "v"(a[0]), "v"(a[1]), "v"(a[2]), "v"(a[3]),
        "s"(0xAAAAAAAAAAAAAAAAull), "s"(0xCCCCCCCCCCCCCCCCull));
  return o;
}

// LDS-only barrier (global prefetch loads stay in flight)
__device__ __forceinline__ void lds_barrier() {
  asm volatile("s_waitcnt lgkmcnt(0)" ::: "memory");
  __builtin_amdgcn_s_barrier();
}

// One workgroup per batch element; 512 threads = 8 waves; grid 256 = 1 block/CU.
// hh: 12 MFMA/wave/step, 4-deep chains per gate (R13 order -- R14's split
// regressed: chain latency is hidden by the 2nd wave/SIMD; issue+overhead rule).
// tau>=1 pipelining: clusters R -> NH -> [R-select+exp] -> Z -> [NH-select]
// -> [Z-select+exp]: gate trans-chain overlaps the MFMA window instead of
// waiting behind a global fence (R13's s_nop x2 + sched_barrier served
// ~500 cyc/step of phase-serial overhead).
// ih: merged into tau=0 (R13 path verbatim, incl. fence); gx[gate][hu][17] f32.
__global__ __launch_bounds__(512) void gru_fused(
    const float* __restrict__ x,        // [B,S,I]
    const int*   __restrict__ mask,     // [B,S,I]
    const float* __restrict__ x_mean,   // [I]
    const float* __restrict__ w_ih,     // [3H,I]
    const float* __restrict__ w_hh,     // [3H,H]
    const float* __restrict__ b_ih,     // [3H]
    const float* __restrict__ b_hh,     // [3H]
    const float* __restrict__ bn_gamma, // [H]
    const float* __restrict__ bn_beta,  // [H]
    const float* __restrict__ bn_mean,  // [H]
    const float* __restrict__ bn_var,   // [H]
    const float* __restrict__ fc_w,     // [1,H]
    const float* __restrict__ fc_b,     // [1]
    float* __restrict__ out)            // [B,1]
{
  const int b   = blockIdx.x;
  const int tid = threadIdx.x;
  const int wv  = tid >> 6;   // wave 0..7
  const int l   = tid & 63;
  const int col = l & 15;     // A row / C-col (= tau in ih-GEMM)
  const int grp = l >> 4;     // k-group

  __shared__ __align__(16) _Float16 h_lds[2][HH];
  __shared__ __align__(16) _Float16 xi_st[GROUP][72];  // [tau][chan], +8 pad
  __shared__ float gx_lds[3][HH][17];                  // [gate][hu][tau], pad 17
  __shared__ float h_fin[HH];

  // ---- A-fragments (weights) -> AGPRs, loaded once ----
  h8 whA[3][4];  // g in {r,z,n} x 4 k-tiles (K=128)
  h8 wiA[3][2];  // g x 2 k-tiles (K=64)
  #pragma unroll
  for (int g = 0; g < 3; ++g) {
    const int row = g * HH + wv * 16 + col;
    #pragma unroll
    for (int kt = 0; kt < 4; ++kt) {
      const float* pw = w_hh + (size_t)row * HH + kt * 32 + grp * 8;
      float4 va = *reinterpret_cast<const float4*>(pw);
      float4 vb = *reinterpret_cast<const float4*>(pw + 4);
      h8 f;
      f[0]=(_Float16)va.x; f[1]=(_Float16)va.y; f[2]=(_Float16)va.z; f[3]=(_Float16)va.w;
      f[4]=(_Float16)vb.x; f[5]=(_Float16)vb.y; f[6]=(_Float16)vb.z; f[7]=(_Float16)vb.w;
      whA[g][kt] = f;
    }
    #pragma unroll
    for (int kt = 0; kt < 2; ++kt) {
      const float* pw = w_ih + (size_t)row * II + kt * 32 + grp * 8;
      float4 va = *reinterpret_cast<const float4*>(pw);
      float4 vb = *reinterpret_cast<const float4*>(pw + 4);
      h8 f;
      f[0]=(_Float16)va.x; f[1]=(_Float16)va.y; f[2]=(_Float16)va.z; f[3]=(_Float16)va.w;
      f[4]=(_Float16)vb.x; f[5]=(_Float16)vb.y; f[6]=(_Float16)vb.z; f[7]=(_Float16)vb.w;
      wiA[g][kt] = f;
    }
  }
  #pragma unroll
  for (int g = 0; g < 3; ++g) {
    #pragma unroll
    for (int kt = 0; kt < 4; ++kt) KEEPA(whA[g][kt]);
    #pragma unroll
    for (int kt = 0; kt < 2; ++kt) KEEPA(wiA[g][kt]);
  }

  // bias C-init fragments
  f4 bRf, bZf, bNXf, bNHf;
  #pragma unroll
  for (int q = 0; q < 4; ++q) {
    const int hu = wv * 16 + grp * 4 + q;
    bRf[q]  = b_ih[hu]        + b_hh[hu];
    bZf[q]  = b_ih[HH + hu]   + b_hh[HH + hu];
    bNXf[q] = b_ih[2*HH + hu];
    bNHf[q] = b_hh[2*HH + hu];
  }
  f4 zf = {0.f, 0.f, 0.f, 0.f};
  KEEPV(bRf); KEEPV(bZf); KEEPV(bNXf); KEEPV(bNHf); KEEPV(zf);

  // per-lane gate slot
  const int q_l  = col & 3;
  const int hu_l = wv * 16 + grp * 4 + q_l;
  const bool cs1 = (col & 1) != 0;
  const bool cs2 = (col & 2) != 0;
  const bool wlead = (col < 4);
  const int hub = wv * 16 + grp * 4;   // gx-write row base

  // ---- LOCF staging: wave 0 (tid<64), one channel each ----
  const size_t xbase = (size_t)b * SS * II;
  const float* xg = x + xbase;
  const int*   mg = mask + xbase;
  float last = 0.f;
  float x_stg[16];
  int   m_stg[16];
  if (tid < 64) {
    last = x_mean[tid];
    #pragma unroll
    for (int u = 0; u < GROUP; ++u) {
      x_stg[u] = xg[u * II + tid];
      m_stg[u] = mg[u * II + tid];
    }
  }
  float ho = 0.f;  // h[t-1][hu_l], f32

  for (int gq = 0; gq < NG; ++gq) {
    // wave0: LOCF -> xi_st (pre-barrier; consumed by all at tau0 post-barrier)
    if (tid < 64) {
      #pragma unroll
      for (int u = 0; u < GROUP; ++u) {
        last = (m_stg[u] > 0) ? x_stg[u] : last;
        xi_st[u][tid] = pack_f16(last, last).x;
      }
    }

    #pragma unroll
    for (int tau = 0; tau < GROUP; ++tau) {
      const int p = tau & 1;
      if (wlead) h_lds[p][hu_l] = pack_f16(ho, ho).x;
      lds_barrier();  // covers h (and xi_st at tau0)

      h8 hB[4];
      #pragma unroll
      for (int kt = 0; kt < 4; ++kt)
        hB[kt] = *reinterpret_cast<const h8*>(&h_lds[p][kt * 32 + grp * 8]);

      if (tau == 0) {
        // ---- R13 tau0 path verbatim (gx not ready early; fenced) ----
        if (tid < 64 && gq + 1 < NG) {
          const float* xn = xg + (size_t)(gq + 1) * GROUP * II;
          const int*   mn = mg + (size_t)(gq + 1) * GROUP * II;
          #pragma unroll
          for (int u = 0; u < GROUP; ++u) {
            x_stg[u] = xn[u * II + tid];
            m_stg[u] = mn[u * II + tid];
          }
        }
        f4 aR  = mfma_first(whA[0][0], hB[0], bRf);
        f4 aZ  = mfma_first(whA[1][0], hB[0], bZf);
        f4 aNH = mfma_first(whA[2][0], hB[0], bNHf);
        #pragma unroll
        for (int kt = 1; kt < 4; ++kt) {
          mfma_acc(aR,  whA[0][kt], hB[kt]);
          mfma_acc(aZ,  whA[1][kt], hB[kt]);
          mfma_acc(aNH, whA[2][kt], hB[kt]);
        }
        // ih-GEMM merged in: 6 MFMAs; chains identical to R12/R13
        h8 xB0 = *reinterpret_cast<const h8*>(&xi_st[col][grp * 8]);
        h8 xB1 = *reinterpret_cast<const h8*>(&xi_st[col][32 + grp * 8]);
        f4 gR  = mfma_first(wiA[0][0], xB0, zf);
        f4 gZ  = mfma_first(wiA[1][0], xB0, zf);
        f4 gNX = mfma_first(wiA[2][0], xB0, bNXf);
        mfma_acc(gR,  wiA[0][1], xB1);
        mfma_acc(gZ,  wiA[1][1], xB1);
        mfma_acc(gNX, wiA[2][1], xB1);
        asm volatile("s_nop 7\n\ts_nop 7");
        __builtin_amdgcn_sched_barrier(0);
        #pragma unroll
        for (int q = 0; q < 4; ++q) {
          gx_lds[0][hub + q][col] = gR[q];
          gx_lds[1][hub + q][col] = gZ[q];
          gx_lds[2][hub + q][col] = gNX[q];
        }
        asm volatile("s_waitcnt lgkmcnt(0)" ::: "memory");
        __builtin_amdgcn_sched_barrier(0);
        const float gxR = gx_lds[0][hu_l][0];
        const float gxZ = gx_lds[1][hu_l][0];
        const float sNX = gx_lds[2][hu_l][0];

        const float sR  = (cs2 ? (cs1 ? aR[3]  : aR[2])  : (cs1 ? aR[1]  : aR[0]))  + gxR;
        const float sZ  = (cs2 ? (cs1 ? aZ[3]  : aZ[2])  : (cs1 ? aZ[1]  : aZ[0]))  + gxZ;
        const float sNH =  cs2 ? (cs1 ? aNH[3] : aNH[2]) : (cs1 ? aNH[1] : aNH[0]);

        float r = fast_rcp(1.f + __expf(-sR));
        float z = fast_rcp(1.f + __expf(-sZ));
        float a = sNX + r * sNH;
        float n = 1.f - 2.f * fast_rcp(__expf(2.f * a) + 1.f);
        ho = n + z * (ho - n);
      } else {
        // ---- pipelined path: gate chain overlaps the MFMA window ----
        const float gxR = gx_lds[0][hu_l][tau];
        const float gxZ = gx_lds[1][hu_l][tau];
        const float sNX = gx_lds[2][hu_l][tau];

        // R cluster (needed first)
        f4 aR = mfma_first(whA[0][0], hB[0], bRf);
        mfma_acc(aR, whA[0][1], hB[1]);
        mfma_acc(aR, whA[0][2], hB[2]);
        mfma_acc(aR, whA[0][3], hB[3]);
        // NH cluster (needed second, feeds the n-chain tail)
        f4 aNH = mfma_first(whA[2][0], hB[0], bNHf);
        mfma_acc(aNH, whA[2][1], hB[1]);
        mfma_acc(aNH, whA[2][2], hB[2]);
        mfma_acc(aNH, whA[2][3], hB[3]);
        // R select+exp: 4 MFMA issues after aR's last write (+s_nop 2)
        float expR = sel_exp(aR, gxR);
        // Z cluster (z needed last, at the blend)
        f4 aZ = mfma_first(whA[1][0], hB[0], bZf);
        mfma_acc(aZ, whA[1][1], hB[1]);
        mfma_acc(aZ, whA[1][2], hB[2]);
        mfma_acc(aZ, whA[1][3], hB[3]);
        // NH select: Rsel(8) + 4 MFMA issues after aNH's last write
        float sNH = sel_nh(aNH);
        // Z select+exp: NHsel(4) + s_nop 2 after aZ's last write
        float expZ = sel_exp(aZ, gxZ);

        // tail (identical arithmetic to R13)
        float r = fast_rcp(1.f + expR);
        float a = sNX + r * sNH;
        float n = 1.f - 2.f * fast_rcp(__expf(2.f * a) + 1.f);
        float z = fast_rcp(1.f + expZ);
        ho = n + z * (ho - n);
      }
    }
  }

  // publish final h (f32)
  if (wlead) h_fin[hu_l] = ho;
  __syncthreads();

  // BN (eval) + FC, reduced by wave 0
  if (tid < 64) {
    float pacc = 0.f;
    #pragma unroll
    for (int q = 0; q < 2; ++q) {
      const int k = tid + q * 64;
      const float hv2 = h_fin[k];
      const float nrm = (hv2 - bn_mean[k]) * rsqrtf(bn_var[k] + 1e-5f) * bn_gamma[k] + bn_beta[k];
      pacc += nrm * fc_w[k];
    }
    #pragma unroll
    for (int off = 32; off > 0; off >>= 1) pacc += __shfl_down(pacc, off);
    if (tid == 0) out[b] = pacc + fc_b[0];
  }
}

extern "C" void kernel_launch(void* const* d_in, const int* in_sizes, int n_in,
                              void* d_out, int out_size, void* d_ws, size_t ws_size,
                              hipStream_t stream) {
  const float* x        = (const float*)d_in[0];
  const int*   mask     = (const int*)  d_in[1];
  // d_in[2] = delta (unused by reference forward)
  const float* x_mean   = (const float*)d_in[3];
  const float* w_ih     = (const float*)d_in[4];
  const float* w_hh     = (const float*)d_in[5];
  const float* b_ih     = (const float*)d_in[6];
  const float* b_hh     = (const float*)d_in[7];
  const float* bn_gamma = (const float*)d_in[8];
  const float* bn_beta  = (const float*)d_in[9];
  const float* bn_mean  = (const float*)d_in[10];
  const float* bn_var   = (const float*)d_in[11];
  const float* fc_w     = (const float*)d_in[12];
  const float* fc_b     = (const float*)d_in[13];
  float* out = (float*)d_out;

  gru_fused<<<dim3(BB), dim3(512), 0, stream>>>(
      x, mask, x_mean, w_ih, w_hh, b_ih, b_hh,
      bn_gamma, bn_beta, bn_mean, bn_var, fc_w, fc_b, out);
}